// Round 3
// baseline (290.781 us; speedup 1.0000x reference)
//
#include <hip/hip_runtime.h>
#include <cstdint>
#include <cstddef>
#include <cmath>

// ---------------------------------------------------------------------------
// Types
// ---------------------------------------------------------------------------
typedef __bf16 bf16x8 __attribute__((ext_vector_type(8)));   // K=32 MFMA A/B frag
typedef float  f32x4  __attribute__((ext_vector_type(4)));   // MFMA C/D frag
typedef unsigned short us4 __attribute__((ext_vector_type(4)));

// float -> bf16, round-to-nearest-even
__device__ __forceinline__ unsigned short f2bf(float f) {
    union { float f; unsigned int u; } v; v.f = f;
    unsigned int u = v.u;
    u += 0x7fffu + ((u >> 16) & 1u);
    return (unsigned short)(u >> 16);
}

__device__ __forceinline__ unsigned int fbits(float f) {
    union { float f; unsigned int u; } v; v.f = f; return v.u;
}

// pack two f32 -> bf16x2 (truncate) in ONE v_perm_b32: low = a, high = b
__device__ __forceinline__ unsigned int pk_bf16_trunc(float a, float b) {
    return __builtin_amdgcn_perm(fbits(b), fbits(a), 0x07060302u);
}

// async global->LDS, 16B per lane; LDS dest = wave-uniform base + lane*16
__device__ __forceinline__ void gld_lds16(const void* g, void* l) {
    __builtin_amdgcn_global_load_lds((__attribute__((address_space(1))) void*)g,
                                     (__attribute__((address_space(3))) void*)l,
                                     16, 0, 0);
}

// ---------------------------------------------------------------------------
// Problem constants
// ---------------------------------------------------------------------------
#define BB   2
#define SS   2048
#define DD   2048
#define HQ   32
#define HKV  8
#define DH   64
#define MM   (BB * SS)          // 4096 tokens
#define NQKV 3072               // 2048 q + 512 k + 512 v

// 0.125 (1/sqrt(DH)) * log2(e) — folded into Wq at transpose_cast2 time so the
// QK^T MFMA output is directly the exp2 argument (softmax shift-invariance
// makes any constant bias a pure power-of-2 factor that cancels in o/l).
#define QSCALE 0.18033688011112042f

// ---------------------------------------------------------------------------
// Kernel: fp32 -> bf16 cast (vectorized)
// ---------------------------------------------------------------------------
__global__ __launch_bounds__(256) void cast_f32_bf16(const float* __restrict__ src,
                                                     unsigned short* __restrict__ dst,
                                                     int n) {
    int i = (blockIdx.x * 256 + threadIdx.x) * 4;
    if (i >= n) return;
    const float4 f = *(const float4*)(src + i);
    us4 o;
    o[0] = f2bf(f.x); o[1] = f2bf(f.y); o[2] = f2bf(f.z); o[3] = f2bf(f.w);
    *(us4*)(dst + i) = o;
}

// ---------------------------------------------------------------------------
// Kernel: batched transpose + cast + scale, 2 matrices per launch (z selects)
// src[R][C] f32 -> dst[C][R] bf16 * scale.  grid = (C/32, R/32, 2), block = 256
// ---------------------------------------------------------------------------
__global__ __launch_bounds__(256) void transpose_cast2(const float* __restrict__ srcA,
                                                       const float* __restrict__ srcB,
                                                       unsigned short* __restrict__ dstA,
                                                       unsigned short* __restrict__ dstB,
                                                       int R, int C,
                                                       float sA, float sB) {
    __shared__ __attribute__((aligned(16))) float tile[32][33];
    const float* src = blockIdx.z ? srcB : srcA;
    unsigned short* dst = blockIdx.z ? dstB : dstA;
    const float scl = blockIdx.z ? sB : sA;
    const int c0 = blockIdx.x * 32, r0 = blockIdx.y * 32;
    const int tx = threadIdx.x & 31, ty = threadIdx.x >> 5;
    #pragma unroll
    for (int dy = 0; dy < 32; dy += 8)
        tile[ty + dy][tx] = src[(size_t)(r0 + ty + dy) * C + c0 + tx];
    __syncthreads();
    #pragma unroll
    for (int dy = 0; dy < 32; dy += 8)
        dst[(size_t)(c0 + ty + dy) * R + r0 + tx] = f2bf(tile[tx][ty + dy] * scl);
}

// ---------------------------------------------------------------------------
// Kernel: transpose V slice of QKV into Vt[b][kvh][d][s]  (bf16 -> bf16)
// grid = (S/32, DH/32, B*HKV), block = 256 (32x8)
// ---------------------------------------------------------------------------
__global__ __launch_bounds__(256) void transpose_v(const unsigned short* __restrict__ qkv,
                                                   unsigned short* __restrict__ vt) {
    __shared__ __attribute__((aligned(16))) unsigned short tile[32][33];
    const int s0 = blockIdx.x * 32, d0 = blockIdx.y * 32;
    const int bh = blockIdx.z;
    const int b = bh >> 3, kvh = bh & 7;
    const int tx = threadIdx.x & 31, ty = threadIdx.x >> 5;
    #pragma unroll
    for (int dy = 0; dy < 32; dy += 8)
        tile[ty + dy][tx] =
            qkv[(size_t)(b * SS + s0 + ty + dy) * NQKV + 2560 + kvh * DH + d0 + tx];
    __syncthreads();
    #pragma unroll
    for (int dy = 0; dy < 32; dy += 8)
        vt[(size_t)((b * HKV + kvh) * DH + d0 + ty + dy) * SS + s0 + tx] =
            tile[tx][ty + dy];
}

// ---------------------------------------------------------------------------
// Kernel: bf16 GEMM, C[M][N] = A[M][K] * Bt[N][K]^T
// 128x128 tile, BK=64, 4 waves (2x2 of 64x64), 16x16x32 MFMA.
// LDS chunk-XOR swizzle -> conflict-free b128 frag reads w/ gld_lds16 staging.
// ---------------------------------------------------------------------------
template <int OUT_BF16>
__global__ __launch_bounds__(256) void gemm_bt(const unsigned short* __restrict__ A,
                                               const unsigned short* __restrict__ Bt,
                                               void* __restrict__ Cout,
                                               int M, int N, int K) {
    __shared__ __attribute__((aligned(16))) unsigned short As[128 * 64];
    __shared__ __attribute__((aligned(16))) unsigned short Bs[128 * 64];
    const int bm = blockIdx.x, bn = blockIdx.y;
    const int tid = threadIdx.x;
    const int wave = tid >> 6, lane = tid & 63;
    const int wm = (wave >> 1) * 64, wn = (wave & 1) * 64;
    const int g = lane >> 4, l15 = lane & 15;
    const int sr = lane >> 3;
    const int sc8 = ((lane & 7) ^ (sr & 7)) * 8;   // swizzled source chunk
    const int r7 = l15 & 7;

    f32x4 acc[4][4] = {};
    const unsigned short* aBase = A  + (size_t)(bm * 128) * K;
    const unsigned short* bBase = Bt + (size_t)(bn * 128) * K;

    for (int kt = 0; kt < K; kt += 64) {
        __syncthreads();
        #pragma unroll
        for (int j = 0; j < 4; ++j) {
            const int i = wave * 4 + j;                      // wave-uniform
            gld_lds16(aBase + (size_t)(i * 8 + sr) * K + kt + sc8, &As[i * 512]);
            gld_lds16(bBase + (size_t)(i * 8 + sr) * K + kt + sc8, &Bs[i * 512]);
        }
        __syncthreads();
        #pragma unroll
        for (int ks = 0; ks < 2; ++ks) {
            bf16x8 af[4], bfr[4];
            #pragma unroll
            for (int t = 0; t < 4; ++t) {
                af[t]  = *(const bf16x8*)&As[(wm + t * 16 + l15) * 64 + ((ks * 4 + g) ^ r7) * 8];
                bfr[t] = *(const bf16x8*)&Bs[(wn + t * 16 + l15) * 64 + ((ks * 4 + g) ^ r7) * 8];
            }
            #pragma unroll
            for (int i = 0; i < 4; ++i)
                #pragma unroll
                for (int j = 0; j < 4; ++j)
                    acc[i][j] = __builtin_amdgcn_mfma_f32_16x16x32_bf16(
                        af[i], bfr[j], acc[i][j], 0, 0, 0);
        }
    }
    // epilogue: C/D layout col = lane&15, row = (lane>>4)*4 + reg
    #pragma unroll
    for (int i = 0; i < 4; ++i) {
        #pragma unroll
        for (int j = 0; j < 4; ++j) {
            const int col = bn * 128 + wn + j * 16 + l15;
            #pragma unroll
            for (int r = 0; r < 4; ++r) {
                const int row = bm * 128 + wm + i * 16 + g * 4 + r;
                const float v = acc[i][j][r];
                if (OUT_BF16)
                    ((unsigned short*)Cout)[(size_t)row * N + col] = f2bf(v);
                else
                    ((float*)Cout)[(size_t)row * N + col] = v;
            }
        }
    }
}

// ---------------------------------------------------------------------------
// Kernel: flash attention v9 — register-resident P at K=32, occupancy fix.
// v8 -> v9 delta (pipes 43/40% but Occupancy 17%: grid 512 blocks = only
// 2 waves/SIMD, so the QK->exp2->pack->PV chain can't be hidden cross-wave):
//  * per-wave q-tile halved 64 -> 32 rows; grid.x doubled (S/128 = 16).
//    1024 blocks = 4 blocks/CU = 4 waves/SIMD (LDS 4x32KB = 128KB <= 160KB).
//    Per-q-row MFMA/exp2 work unchanged; VGPR drops ~64 (oacc/qf/lacc/pk4
//    halve) so registers don't cap occupancy. Staging structure unchanged
//    (waves 0-1 stage K, 2-3 stage V; K/V re-reads are L2-resident).
// grid = (S/128, HQ, B), block = 256 (4 waves x 32 q)
// ---------------------------------------------------------------------------
__global__ __launch_bounds__(256, 4) void flash_attn(const unsigned short* __restrict__ qkv,
                                                     const unsigned short* __restrict__ vt,
                                                     unsigned short* __restrict__ ctx) {
    __shared__ __attribute__((aligned(16))) unsigned short Ks[2][64 * 64];   // [permuted key][dh] swz
    __shared__ __attribute__((aligned(16))) unsigned short Vs[2][64 * 64];   // [dh][key] swz

    const int qt = blockIdx.x, h = blockIdx.y, b = blockIdx.z;
    const int kvh = h >> 2;   // NUM_REP = 4
    const int tid = threadIdx.x, wave = tid >> 6, lane = tid & 63;
    const int g = lane >> 4, l15 = lane & 15;
    const int sr = lane >> 3;
    const int sc8 = ((lane & 7) ^ (sr & 7)) * 8;
    const int r7 = l15 & 7;
    const int qb = qt * 128 + wave * 32;

    const unsigned short* kbase = qkv + (size_t)(b * SS) * NQKV + 2048 + kvh * DH;
    const unsigned short* vbase = vt + (size_t)((b * HKV + kvh) * DH) * SS;

    // Q fragments, B-operand layout (n-col = l15, k = g*8+j): [q n-tile][k-half]
    bf16x8 qf[2][2];
    #pragma unroll
    for (int n = 0; n < 2; ++n)
        #pragma unroll
        for (int kh = 0; kh < 2; ++kh)
            qf[n][kh] = *(const bf16x8*)(qkv +
                (size_t)(b * SS + qb + n * 16 + l15) * NQKV + h * DH + kh * 32 + g * 8);

    // all-ones B fragment for the denominator MFMA (any layout: every elem 1)
    bf16x8 ones;
    #pragma unroll
    for (int i = 0; i < 8; ++i) ones[i] = (__bf16)1.0f;

    // per-lane staging pointers (advanced by constant each iter; no per-iter mul)
    const unsigned short* sp[4];
    size_t sadv;
    if (wave < 2) {
        #pragma unroll
        for (int j = 0; j < 4; ++j) {
            const int rho = (wave * 4 + j) * 8 + sr;       // LDS row this lane fills
            // bit-swap: rho=[p,h,g1,g0,r1,r0] -> physical key=[p,g1,g0,h,r1,r0]
            const int key = (rho & 0x23) | ((rho & 0x0C) << 1) | ((rho & 0x10) >> 2);
            sp[j] = kbase + (size_t)key * NQKV + sc8;
        }
        sadv = (size_t)64 * NQKV;          // next 64 keys
    } else {
        #pragma unroll
        for (int j = 0; j < 4; ++j)
            sp[j] = vbase + (size_t)(((wave - 2) * 4 + j) * 8 + sr) * SS + sc8;
        sadv = 64;                          // next 64 keys (columns of Vt)
    }

    #define STAGE(buf)                                                        \
        do {                                                                  \
            if (wave < 2) {                                                   \
                _Pragma("unroll")                                             \
                for (int j = 0; j < 4; ++j)                                   \
                    gld_lds16(sp[j], &Ks[buf][(wave * 4 + j) * 512]);         \
            } else {                                                          \
                _Pragma("unroll")                                             \
                for (int j = 0; j < 4; ++j)                                   \
                    gld_lds16(sp[j], &Vs[buf][((wave - 2) * 4 + j) * 512]);   \
            }                                                                 \
            _Pragma("unroll")                                                 \
            for (int j = 0; j < 4; ++j) sp[j] += sadv;                        \
        } while (0)

    f32x4 oacc[2][4] = {};        // [q m-tile][dh n-tile]
    f32x4 lacc[2] = {};           // denominator accum: lacc[m][r] = rowsum(q=m*16+g*4+r)

    STAGE(0);
    int cur = 0;

    for (int kt = 0; kt < SS; kt += 64) {
        // compiler emits s_waitcnt vmcnt(0) before s_barrier -> buf[cur] ready
        __syncthreads();
        if (kt + 64 < SS) { STAGE(cur ^ 1); }   // prefetch hidden behind compute

        const unsigned short* ks = Ks[cur];
        const unsigned short* vs = Vs[cur];

        // per 32-key chunk p: two Sᵀ tiles (QK K=32) -> exp -> concat packs
        // ARE the K=32 P A-frag -> PV at K=32
        #pragma unroll
        for (int p = 0; p < 2; ++p) {
            uint4 pk4[2];                       // P A-frags being assembled
            #pragma unroll
            for (int hh = 0; hh < 2; ++hh) {
                const int t = 2 * p + hh;
                bf16x8 kf0 = *(const bf16x8*)&ks[(t * 16 + l15) * 64 + ((g) ^ r7) * 8];
                bf16x8 kf1 = *(const bf16x8*)&ks[(t * 16 + l15) * 64 + ((4 + g) ^ r7) * 8];
                #pragma unroll
                for (int n = 0; n < 2; ++n) {
                    f32x4 c = {};
                    c = __builtin_amdgcn_mfma_f32_16x16x32_bf16(kf0, qf[n][0], c, 0, 0, 0);
                    c = __builtin_amdgcn_mfma_f32_16x16x32_bf16(kf1, qf[n][1], c, 0, 0, 0);
                    // Wq pre-scaled by 0.125*log2(e): c IS the exp2 argument
                    f32x4 pe;
                    pe[0] = __builtin_amdgcn_exp2f(c[0]);
                    pe[1] = __builtin_amdgcn_exp2f(c[1]);
                    pe[2] = __builtin_amdgcn_exp2f(c[2]);
                    pe[3] = __builtin_amdgcn_exp2f(c[3]);
                    const unsigned int lo = pk_bf16_trunc(pe[0], pe[1]);
                    const unsigned int hi = pk_bf16_trunc(pe[2], pe[3]);
                    if (hh == 0) { pk4[n].x = lo; pk4[n].y = hi; }
                    else         { pk4[n].z = lo; pk4[n].w = hi; }
                }
            }
            // O += P(p) @ V(p) at K=32: A = P regs, B = Vs[dh][keys p*32+g*8..+7]
            // denominator rides along: lacc[m] += P(p) @ 1 (matrix pipe, not VALU)
            __builtin_amdgcn_s_setprio(1);
            #pragma unroll
            for (int nt = 0; nt < 4; ++nt) {
                bf16x8 vf = *(const bf16x8*)&vs[(nt * 16 + l15) * 64 +
                                                (((p << 2) + g) ^ r7) * 8];
                #pragma unroll
                for (int m = 0; m < 2; ++m) {
                    union { uint4 u; bf16x8 v; } pa; pa.u = pk4[m];
                    oacc[m][nt] = __builtin_amdgcn_mfma_f32_16x16x32_bf16(
                        pa.v, vf, oacc[m][nt], 0, 0, 0);
                    if (nt == 0)
                        lacc[m] = __builtin_amdgcn_mfma_f32_16x16x32_bf16(
                            pa.v, ones, lacc[m], 0, 0, 0);
                }
            }
            __builtin_amdgcn_s_setprio(0);
        }
        cur ^= 1;
    }

    // normalize + write: lane (g,l15) holds O[q = m*16+g*4+r][dh = nt*16+l15];
    // lacc[m][r] is the matching row denominator in the SAME lane (ones-MFMA
    // C/D layout row = g*4+r) -> no cross-lane reduce needed.
    #pragma unroll
    for (int m = 0; m < 2; ++m) {
        #pragma unroll
        for (int r = 0; r < 4; ++r) {
            const float inv = 1.0f / lacc[m][r];
            const int token = b * SS + qb + m * 16 + g * 4 + r;
            #pragma unroll
            for (int nt = 0; nt < 4; ++nt)
                ctx[(size_t)token * (HQ * DH) + h * DH + nt * 16 + l15] =
                    f2bf(oacc[m][nt][r] * inv);
        }
    }
    #undef STAGE
}

// ---------------------------------------------------------------------------
// Launcher
// ---------------------------------------------------------------------------
extern "C" void kernel_launch(void* const* d_in, const int* in_sizes, int n_in,
                              void* d_out, int out_size, void* d_ws, size_t ws_size,
                              hipStream_t stream) {
    (void)in_sizes; (void)n_in; (void)out_size; (void)ws_size;
    const float* x  = (const float*)d_in[0];
    const float* Wq = (const float*)d_in[1];
    const float* Wk = (const float*)d_in[2];
    const float* Wv = (const float*)d_in[3];
    const float* Wo = (const float*)d_in[4];
    float* out = (float*)d_out;

    char* ws = (char*)d_ws;
    unsigned short* xb     = (unsigned short*)(ws);                         // 16 MB
    unsigned short* WqkvT  = (unsigned short*)(ws + 16777216);              // 12 MB  [3072][2048]
    unsigned short* WoT    = (unsigned short*)(ws + 29360128);              // 8 MB   [2048][2048]
    unsigned short* QKV    = (unsigned short*)(ws + 37748736);              // 24 MB  [4096][3072]
    unsigned short* Vt     = (unsigned short*)(ws + 62914560);              // 4 MB   [16][64][2048]
    unsigned short* ctx    = (unsigned short*)(ws + 67108864);              // 16 MB  [4096][2048]
    // total 80 MB

    // 1) casts / transposes (batched: Wq+Wo, then Wk+Wv).
    //    Wq is pre-scaled by 0.125*log2(e) so flash_attn's QK output feeds
    //    exp2 directly (softmax is shift/scale-consistent; see kernel note).
    cast_f32_bf16<<<8192, 256, 0, stream>>>(x, xb, MM * DD);
    transpose_cast2<<<dim3(64, 64, 2), 256, 0, stream>>>(Wq, Wo, WqkvT, WoT, 2048, 2048,
                                                         QSCALE, 1.0f);
    transpose_cast2<<<dim3(16, 64, 2), 256, 0, stream>>>(
        Wk, Wv, WqkvT + (size_t)2048 * 2048, WqkvT + (size_t)2560 * 2048, 2048, 512,
        1.0f, 1.0f);

    // 2) fused QKV projection: [4096,2048] @ [2048,3072] -> QKV bf16
    gemm_bt<1><<<dim3(32, 24), 256, 0, stream>>>(xb, WqkvT, QKV, MM, NQKV, DD);

    // 3) V transpose for PV fragment layout
    transpose_v<<<dim3(64, 2, 16), 256, 0, stream>>>(QKV, Vt);

    // 4) flash attention v9 -> ctx bf16
    flash_attn<<<dim3(16, 32, 2), 256, 0, stream>>>(QKV, Vt, ctx);

    // 5) output projection: [4096,2048] @ [2048,2048] -> out fp32
    gemm_bt<0><<<dim3(32, 16), 256, 0, stream>>>(ctx, WoT, out, MM, DD, DD);
}

// Round 4
// 290.687 us; speedup vs baseline: 1.0003x; 1.0003x over previous
//
#include <hip/hip_runtime.h>
#include <cstdint>
#include <cstddef>
#include <cmath>

// ---------------------------------------------------------------------------
// Types
// ---------------------------------------------------------------------------
typedef __bf16 bf16x8 __attribute__((ext_vector_type(8)));   // K=32 MFMA A/B frag
typedef float  f32x4  __attribute__((ext_vector_type(4)));   // MFMA C/D frag
typedef unsigned short us4 __attribute__((ext_vector_type(4)));

// float -> bf16, round-to-nearest-even
__device__ __forceinline__ unsigned short f2bf(float f) {
    union { float f; unsigned int u; } v; v.f = f;
    unsigned int u = v.u;
    u += 0x7fffu + ((u >> 16) & 1u);
    return (unsigned short)(u >> 16);
}

__device__ __forceinline__ unsigned int fbits(float f) {
    union { float f; unsigned int u; } v; v.f = f; return v.u;
}

// pack two f32 -> bf16x2 (truncate) in ONE v_perm_b32: low = a, high = b
__device__ __forceinline__ unsigned int pk_bf16_trunc(float a, float b) {
    return __builtin_amdgcn_perm(fbits(b), fbits(a), 0x07060302u);
}

// async global->LDS, 16B per lane; LDS dest = wave-uniform base + lane*16
__device__ __forceinline__ void gld_lds16(const void* g, void* l) {
    __builtin_amdgcn_global_load_lds((__attribute__((address_space(1))) void*)g,
                                     (__attribute__((address_space(3))) void*)l,
                                     16, 0, 0);
}

// ---------------------------------------------------------------------------
// Problem constants
// ---------------------------------------------------------------------------
#define BB   2
#define SS   2048
#define DD   2048
#define HQ   32
#define HKV  8
#define DH   64
#define MM   (BB * SS)          // 4096 tokens
#define NQKV 3072               // 2048 q + 512 k + 512 v

// 0.125 (1/sqrt(DH)) * log2(e) — folded into Wq at transpose_cast2 time so the
// QK^T MFMA output is directly the exp2 argument (softmax shift-invariance
// makes any constant bias a pure power-of-2 factor that cancels in o/l).
#define QSCALE 0.18033688011112042f

// ---------------------------------------------------------------------------
// Kernel: fp32 -> bf16 cast (vectorized)
// ---------------------------------------------------------------------------
__global__ __launch_bounds__(256) void cast_f32_bf16(const float* __restrict__ src,
                                                     unsigned short* __restrict__ dst,
                                                     int n) {
    int i = (blockIdx.x * 256 + threadIdx.x) * 4;
    if (i >= n) return;
    const float4 f = *(const float4*)(src + i);
    us4 o;
    o[0] = f2bf(f.x); o[1] = f2bf(f.y); o[2] = f2bf(f.z); o[3] = f2bf(f.w);
    *(us4*)(dst + i) = o;
}

// ---------------------------------------------------------------------------
// Kernel: batched transpose + cast + scale, 2 matrices per launch (z selects)
// src[R][C] f32 -> dst[C][R] bf16 * scale.  grid = (C/32, R/32, 2), block = 256
// ---------------------------------------------------------------------------
__global__ __launch_bounds__(256) void transpose_cast2(const float* __restrict__ srcA,
                                                       const float* __restrict__ srcB,
                                                       unsigned short* __restrict__ dstA,
                                                       unsigned short* __restrict__ dstB,
                                                       int R, int C,
                                                       float sA, float sB) {
    __shared__ __attribute__((aligned(16))) float tile[32][33];
    const float* src = blockIdx.z ? srcB : srcA;
    unsigned short* dst = blockIdx.z ? dstB : dstA;
    const float scl = blockIdx.z ? sB : sA;
    const int c0 = blockIdx.x * 32, r0 = blockIdx.y * 32;
    const int tx = threadIdx.x & 31, ty = threadIdx.x >> 5;
    #pragma unroll
    for (int dy = 0; dy < 32; dy += 8)
        tile[ty + dy][tx] = src[(size_t)(r0 + ty + dy) * C + c0 + tx];
    __syncthreads();
    #pragma unroll
    for (int dy = 0; dy < 32; dy += 8)
        dst[(size_t)(c0 + ty + dy) * R + r0 + tx] = f2bf(tile[tx][ty + dy] * scl);
}

// ---------------------------------------------------------------------------
// Kernel: transpose V slice of QKV into Vt[b][kvh][d][s]  (bf16 -> bf16)
// grid = (S/32, DH/32, B*HKV), block = 256 (32x8)
// ---------------------------------------------------------------------------
__global__ __launch_bounds__(256) void transpose_v(const unsigned short* __restrict__ qkv,
                                                   unsigned short* __restrict__ vt) {
    __shared__ __attribute__((aligned(16))) unsigned short tile[32][33];
    const int s0 = blockIdx.x * 32, d0 = blockIdx.y * 32;
    const int bh = blockIdx.z;
    const int b = bh >> 3, kvh = bh & 7;
    const int tx = threadIdx.x & 31, ty = threadIdx.x >> 5;
    #pragma unroll
    for (int dy = 0; dy < 32; dy += 8)
        tile[ty + dy][tx] =
            qkv[(size_t)(b * SS + s0 + ty + dy) * NQKV + 2560 + kvh * DH + d0 + tx];
    __syncthreads();
    #pragma unroll
    for (int dy = 0; dy < 32; dy += 8)
        vt[(size_t)((b * HKV + kvh) * DH + d0 + ty + dy) * SS + s0 + tx] =
            tile[tx][ty + dy];
}

// ---------------------------------------------------------------------------
// Kernel: bf16 GEMM, C[M][N] = A[M][K] * Bt[N][K]^T
// 128x128 tile, BK=64, 4 waves (2x2 of 64x64), 16x16x32 MFMA.
// LDS chunk-XOR swizzle -> conflict-free b128 frag reads w/ gld_lds16 staging.
// ---------------------------------------------------------------------------
template <int OUT_BF16>
__global__ __launch_bounds__(256) void gemm_bt(const unsigned short* __restrict__ A,
                                               const unsigned short* __restrict__ Bt,
                                               void* __restrict__ Cout,
                                               int M, int N, int K) {
    __shared__ __attribute__((aligned(16))) unsigned short As[128 * 64];
    __shared__ __attribute__((aligned(16))) unsigned short Bs[128 * 64];
    const int bm = blockIdx.x, bn = blockIdx.y;
    const int tid = threadIdx.x;
    const int wave = tid >> 6, lane = tid & 63;
    const int wm = (wave >> 1) * 64, wn = (wave & 1) * 64;
    const int g = lane >> 4, l15 = lane & 15;
    const int sr = lane >> 3;
    const int sc8 = ((lane & 7) ^ (sr & 7)) * 8;   // swizzled source chunk
    const int r7 = l15 & 7;

    f32x4 acc[4][4] = {};
    const unsigned short* aBase = A  + (size_t)(bm * 128) * K;
    const unsigned short* bBase = Bt + (size_t)(bn * 128) * K;

    for (int kt = 0; kt < K; kt += 64) {
        __syncthreads();
        #pragma unroll
        for (int j = 0; j < 4; ++j) {
            const int i = wave * 4 + j;                      // wave-uniform
            gld_lds16(aBase + (size_t)(i * 8 + sr) * K + kt + sc8, &As[i * 512]);
            gld_lds16(bBase + (size_t)(i * 8 + sr) * K + kt + sc8, &Bs[i * 512]);
        }
        __syncthreads();
        #pragma unroll
        for (int ks = 0; ks < 2; ++ks) {
            bf16x8 af[4], bfr[4];
            #pragma unroll
            for (int t = 0; t < 4; ++t) {
                af[t]  = *(const bf16x8*)&As[(wm + t * 16 + l15) * 64 + ((ks * 4 + g) ^ r7) * 8];
                bfr[t] = *(const bf16x8*)&Bs[(wn + t * 16 + l15) * 64 + ((ks * 4 + g) ^ r7) * 8];
            }
            #pragma unroll
            for (int i = 0; i < 4; ++i)
                #pragma unroll
                for (int j = 0; j < 4; ++j)
                    acc[i][j] = __builtin_amdgcn_mfma_f32_16x16x32_bf16(
                        af[i], bfr[j], acc[i][j], 0, 0, 0);
        }
    }
    // epilogue: C/D layout col = lane&15, row = (lane>>4)*4 + reg
    #pragma unroll
    for (int i = 0; i < 4; ++i) {
        #pragma unroll
        for (int j = 0; j < 4; ++j) {
            const int col = bn * 128 + wn + j * 16 + l15;
            #pragma unroll
            for (int r = 0; r < 4; ++r) {
                const int row = bm * 128 + wm + i * 16 + g * 4 + r;
                const float v = acc[i][j][r];
                if (OUT_BF16)
                    ((unsigned short*)Cout)[(size_t)row * N + col] = f2bf(v);
                else
                    ((float*)Cout)[(size_t)row * N + col] = v;
            }
        }
    }
}

// ---------------------------------------------------------------------------
// Kernel: flash attention v10 — intra-tile software pipeline.
// v9 -> v10 delta (MfmaUtil 46 / VALUBusy 47, both pipes half-idle: the
// per-chunk QK->exp2->pack->PV sequence is serial per wave, and the old
// setprio fence between chunks stopped the scheduler from interleaving):
//  * chunk p=1's 8 QK MFMAs are issued right after chunk p=0's softmax
//    (independent chains); exp2/pack of p=1 is interleaved into the PV(p=0)
//    nt-steps, so one wave feeds MFMA and VALU/TRANS pipes simultaneously.
//  * setprio(1) hoisted over the whole MFMA-dense interleaved region; the
//    latency-exposed QK(p0) head runs at prio 0 (other waves preempt).
//  * kernel-lifetime zero f32x4 reused as the QK C-operand (no per-chain
//    4x v_mov zero-init).
// grid = (S/128, HQ, B), block = 256 (4 waves x 32 q)
// ---------------------------------------------------------------------------
__global__ __launch_bounds__(256, 4) void flash_attn(const unsigned short* __restrict__ qkv,
                                                     const unsigned short* __restrict__ vt,
                                                     unsigned short* __restrict__ ctx) {
    __shared__ __attribute__((aligned(16))) unsigned short Ks[2][64 * 64];   // [permuted key][dh] swz
    __shared__ __attribute__((aligned(16))) unsigned short Vs[2][64 * 64];   // [dh][key] swz

    const int qt = blockIdx.x, h = blockIdx.y, b = blockIdx.z;
    const int kvh = h >> 2;   // NUM_REP = 4
    const int tid = threadIdx.x, wave = tid >> 6, lane = tid & 63;
    const int g = lane >> 4, l15 = lane & 15;
    const int sr = lane >> 3;
    const int sc8 = ((lane & 7) ^ (sr & 7)) * 8;
    const int r7 = l15 & 7;
    const int qb = qt * 128 + wave * 32;

    const unsigned short* kbase = qkv + (size_t)(b * SS) * NQKV + 2048 + kvh * DH;
    const unsigned short* vbase = vt + (size_t)((b * HKV + kvh) * DH) * SS;

    // Q fragments, B-operand layout (n-col = l15, k = g*8+j): [q n-tile][k-half]
    bf16x8 qf[2][2];
    #pragma unroll
    for (int n = 0; n < 2; ++n)
        #pragma unroll
        for (int kh = 0; kh < 2; ++kh)
            qf[n][kh] = *(const bf16x8*)(qkv +
                (size_t)(b * SS + qb + n * 16 + l15) * NQKV + h * DH + kh * 32 + g * 8);

    // all-ones B fragment for the denominator MFMA (any layout: every elem 1)
    bf16x8 ones;
    #pragma unroll
    for (int i = 0; i < 8; ++i) ones[i] = (__bf16)1.0f;

    // kernel-lifetime zero C-operand for QK chains (never written)
    const f32x4 z4 = {0.0f, 0.0f, 0.0f, 0.0f};

    // per-lane staging pointers (advanced by constant each iter; no per-iter mul)
    const unsigned short* sp[4];
    size_t sadv;
    if (wave < 2) {
        #pragma unroll
        for (int j = 0; j < 4; ++j) {
            const int rho = (wave * 4 + j) * 8 + sr;       // LDS row this lane fills
            // bit-swap: rho=[p,h,g1,g0,r1,r0] -> physical key=[p,g1,g0,h,r1,r0]
            const int key = (rho & 0x23) | ((rho & 0x0C) << 1) | ((rho & 0x10) >> 2);
            sp[j] = kbase + (size_t)key * NQKV + sc8;
        }
        sadv = (size_t)64 * NQKV;          // next 64 keys
    } else {
        #pragma unroll
        for (int j = 0; j < 4; ++j)
            sp[j] = vbase + (size_t)(((wave - 2) * 4 + j) * 8 + sr) * SS + sc8;
        sadv = 64;                          // next 64 keys (columns of Vt)
    }

    #define STAGE(buf)                                                        \
        do {                                                                  \
            if (wave < 2) {                                                   \
                _Pragma("unroll")                                             \
                for (int j = 0; j < 4; ++j)                                   \
                    gld_lds16(sp[j], &Ks[buf][(wave * 4 + j) * 512]);         \
            } else {                                                          \
                _Pragma("unroll")                                             \
                for (int j = 0; j < 4; ++j)                                   \
                    gld_lds16(sp[j], &Vs[buf][((wave - 2) * 4 + j) * 512]);   \
            }                                                                 \
            _Pragma("unroll")                                                 \
            for (int j = 0; j < 4; ++j) sp[j] += sadv;                        \
        } while (0)

    f32x4 oacc[2][4] = {};        // [q m-tile][dh n-tile]
    f32x4 lacc[2] = {};           // denominator accum: lacc[m][r] = rowsum(q=m*16+g*4+r)

    STAGE(0);
    int cur = 0;

    for (int kt = 0; kt < SS; kt += 64) {
        // compiler emits s_waitcnt vmcnt(0) before s_barrier -> buf[cur] ready
        __syncthreads();
        if (kt + 64 < SS) { STAGE(cur ^ 1); }   // prefetch hidden behind compute

        const unsigned short* ks = Ks[cur];
        const unsigned short* vs = Vs[cur];

        // ---- chunk p=0: QK (K=64 via two K=32 steps) -> exp2 -> pack ----
        uint4 pkA[2];
        #pragma unroll
        for (int hh = 0; hh < 2; ++hh) {
            bf16x8 kf0 = *(const bf16x8*)&ks[(hh * 16 + l15) * 64 + ((g) ^ r7) * 8];
            bf16x8 kf1 = *(const bf16x8*)&ks[(hh * 16 + l15) * 64 + ((4 + g) ^ r7) * 8];
            #pragma unroll
            for (int n = 0; n < 2; ++n) {
                f32x4 c = __builtin_amdgcn_mfma_f32_16x16x32_bf16(kf0, qf[n][0], z4, 0, 0, 0);
                c = __builtin_amdgcn_mfma_f32_16x16x32_bf16(kf1, qf[n][1], c, 0, 0, 0);
                f32x4 pe;
                pe[0] = __builtin_amdgcn_exp2f(c[0]);
                pe[1] = __builtin_amdgcn_exp2f(c[1]);
                pe[2] = __builtin_amdgcn_exp2f(c[2]);
                pe[3] = __builtin_amdgcn_exp2f(c[3]);
                const unsigned int lo = pk_bf16_trunc(pe[0], pe[1]);
                const unsigned int hi = pk_bf16_trunc(pe[2], pe[3]);
                if (hh == 0) { pkA[n].x = lo; pkA[n].y = hi; }
                else         { pkA[n].z = lo; pkA[n].w = hi; }
            }
        }

        // ---- chunk p=1: issue all 8 QK MFMAs early (results consumed below,
        //      latency hidden under PV(p=0)) ----
        f32x4 cB[2][2];   // [hh][n]
        #pragma unroll
        for (int hh = 0; hh < 2; ++hh) {
            const int t = 2 + hh;
            bf16x8 kf0 = *(const bf16x8*)&ks[(t * 16 + l15) * 64 + ((g) ^ r7) * 8];
            bf16x8 kf1 = *(const bf16x8*)&ks[(t * 16 + l15) * 64 + ((4 + g) ^ r7) * 8];
            #pragma unroll
            for (int n = 0; n < 2; ++n) {
                cB[hh][n] = __builtin_amdgcn_mfma_f32_16x16x32_bf16(kf0, qf[n][0], z4, 0, 0, 0);
                cB[hh][n] = __builtin_amdgcn_mfma_f32_16x16x32_bf16(kf1, qf[n][1], cB[hh][n], 0, 0, 0);
            }
        }

        __builtin_amdgcn_s_setprio(1);
        // ---- interleaved: PV(p=0) nt-steps + exp2/pack of p=1 ----
        uint4 pkB[2];
        #pragma unroll
        for (int nt = 0; nt < 4; ++nt) {
            bf16x8 vf = *(const bf16x8*)&vs[(nt * 16 + l15) * 64 + ((g) ^ r7) * 8];
            #pragma unroll
            for (int m = 0; m < 2; ++m) {
                union { uint4 u; bf16x8 v; } pa; pa.u = pkA[m];
                oacc[m][nt] = __builtin_amdgcn_mfma_f32_16x16x32_bf16(
                    pa.v, vf, oacc[m][nt], 0, 0, 0);
            }
            if (nt == 0) {
                #pragma unroll
                for (int m = 0; m < 2; ++m) {
                    union { uint4 u; bf16x8 v; } pa; pa.u = pkA[m];
                    lacc[m] = __builtin_amdgcn_mfma_f32_16x16x32_bf16(
                        pa.v, ones, lacc[m], 0, 0, 0);
                }
            }
            if (nt < 2) {
                const int hh = nt;   // softmax slice for chunk p=1
                #pragma unroll
                for (int n = 0; n < 2; ++n) {
                    f32x4 pe;
                    pe[0] = __builtin_amdgcn_exp2f(cB[hh][n][0]);
                    pe[1] = __builtin_amdgcn_exp2f(cB[hh][n][1]);
                    pe[2] = __builtin_amdgcn_exp2f(cB[hh][n][2]);
                    pe[3] = __builtin_amdgcn_exp2f(cB[hh][n][3]);
                    const unsigned int lo = pk_bf16_trunc(pe[0], pe[1]);
                    const unsigned int hi = pk_bf16_trunc(pe[2], pe[3]);
                    if (hh == 0) { pkB[n].x = lo; pkB[n].y = hi; }
                    else         { pkB[n].z = lo; pkB[n].w = hi; }
                }
            }
        }
        // ---- PV(p=1) ----
        #pragma unroll
        for (int nt = 0; nt < 4; ++nt) {
            bf16x8 vf = *(const bf16x8*)&vs[(nt * 16 + l15) * 64 + ((4 + g) ^ r7) * 8];
            #pragma unroll
            for (int m = 0; m < 2; ++m) {
                union { uint4 u; bf16x8 v; } pa; pa.u = pkB[m];
                oacc[m][nt] = __builtin_amdgcn_mfma_f32_16x16x32_bf16(
                    pa.v, vf, oacc[m][nt], 0, 0, 0);
            }
            if (nt == 0) {
                #pragma unroll
                for (int m = 0; m < 2; ++m) {
                    union { uint4 u; bf16x8 v; } pa; pa.u = pkB[m];
                    lacc[m] = __builtin_amdgcn_mfma_f32_16x16x32_bf16(
                        pa.v, ones, lacc[m], 0, 0, 0);
                }
            }
        }
        __builtin_amdgcn_s_setprio(0);

        cur ^= 1;
    }

    // normalize + write: lane (g,l15) holds O[q = m*16+g*4+r][dh = nt*16+l15];
    // lacc[m][r] is the matching row denominator in the SAME lane (ones-MFMA
    // C/D layout row = g*4+r) -> no cross-lane reduce needed.
    #pragma unroll
    for (int m = 0; m < 2; ++m) {
        #pragma unroll
        for (int r = 0; r < 4; ++r) {
            const float inv = 1.0f / lacc[m][r];
            const int token = b * SS + qb + m * 16 + g * 4 + r;
            #pragma unroll
            for (int nt = 0; nt < 4; ++nt)
                ctx[(size_t)token * (HQ * DH) + h * DH + nt * 16 + l15] =
                    f2bf(oacc[m][nt][r] * inv);
        }
    }
    #undef STAGE
}

// ---------------------------------------------------------------------------
// Launcher
// ---------------------------------------------------------------------------
extern "C" void kernel_launch(void* const* d_in, const int* in_sizes, int n_in,
                              void* d_out, int out_size, void* d_ws, size_t ws_size,
                              hipStream_t stream) {
    (void)in_sizes; (void)n_in; (void)out_size; (void)ws_size;
    const float* x  = (const float*)d_in[0];
    const float* Wq = (const float*)d_in[1];
    const float* Wk = (const float*)d_in[2];
    const float* Wv = (const float*)d_in[3];
    const float* Wo = (const float*)d_in[4];
    float* out = (float*)d_out;

    char* ws = (char*)d_ws;
    unsigned short* xb     = (unsigned short*)(ws);                         // 16 MB
    unsigned short* WqkvT  = (unsigned short*)(ws + 16777216);              // 12 MB  [3072][2048]
    unsigned short* WoT    = (unsigned short*)(ws + 29360128);              // 8 MB   [2048][2048]
    unsigned short* QKV    = (unsigned short*)(ws + 37748736);              // 24 MB  [4096][3072]
    unsigned short* Vt     = (unsigned short*)(ws + 62914560);              // 4 MB   [16][64][2048]
    unsigned short* ctx    = (unsigned short*)(ws + 67108864);              // 16 MB  [4096][2048]
    // total 80 MB

    // 1) casts / transposes (batched: Wq+Wo, then Wk+Wv).
    //    Wq is pre-scaled by 0.125*log2(e) so flash_attn's QK output feeds
    //    exp2 directly (softmax is shift/scale-consistent; see kernel note).
    cast_f32_bf16<<<8192, 256, 0, stream>>>(x, xb, MM * DD);
    transpose_cast2<<<dim3(64, 64, 2), 256, 0, stream>>>(Wq, Wo, WqkvT, WoT, 2048, 2048,
                                                         QSCALE, 1.0f);
    transpose_cast2<<<dim3(16, 64, 2), 256, 0, stream>>>(
        Wk, Wv, WqkvT + (size_t)2048 * 2048, WqkvT + (size_t)2560 * 2048, 2048, 512,
        1.0f, 1.0f);

    // 2) fused QKV projection: [4096,2048] @ [2048,3072] -> QKV bf16
    gemm_bt<1><<<dim3(32, 24), 256, 0, stream>>>(xb, WqkvT, QKV, MM, NQKV, DD);

    // 3) V transpose for PV fragment layout
    transpose_v<<<dim3(64, 2, 16), 256, 0, stream>>>(QKV, Vt);

    // 4) flash attention v10 -> ctx bf16
    flash_attn<<<dim3(16, 32, 2), 256, 0, stream>>>(QKV, Vt, ctx);

    // 5) output projection: [4096,2048] @ [2048,2048] -> out fp32
    gemm_bt<0><<<dim3(32, 16), 256, 0, stream>>>(ctx, WoT, out, MM, DD, DD);
}

// Round 5
// 287.152 us; speedup vs baseline: 1.0126x; 1.0123x over previous
//
#include <hip/hip_runtime.h>
#include <cstdint>
#include <cstddef>
#include <cmath>

// ---------------------------------------------------------------------------
// Types
// ---------------------------------------------------------------------------
typedef __bf16 bf16x8 __attribute__((ext_vector_type(8)));   // K=32 MFMA A/B frag
typedef float  f32x4  __attribute__((ext_vector_type(4)));   // MFMA C/D frag
typedef unsigned short us4 __attribute__((ext_vector_type(4)));

// float -> bf16, round-to-nearest-even
__device__ __forceinline__ unsigned short f2bf(float f) {
    union { float f; unsigned int u; } v; v.f = f;
    unsigned int u = v.u;
    u += 0x7fffu + ((u >> 16) & 1u);
    return (unsigned short)(u >> 16);
}

__device__ __forceinline__ unsigned int fbits(float f) {
    union { float f; unsigned int u; } v; v.f = f; return v.u;
}

// pack two f32 -> bf16x2 (truncate) in ONE v_perm_b32: low = a, high = b
__device__ __forceinline__ unsigned int pk_bf16_trunc(float a, float b) {
    return __builtin_amdgcn_perm(fbits(b), fbits(a), 0x07060302u);
}

// async global->LDS, 16B per lane; LDS dest = wave-uniform base + lane*16
__device__ __forceinline__ void gld_lds16(const void* g, void* l) {
    __builtin_amdgcn_global_load_lds((__attribute__((address_space(1))) void*)g,
                                     (__attribute__((address_space(3))) void*)l,
                                     16, 0, 0);
}

// ---------------------------------------------------------------------------
// Problem constants
// ---------------------------------------------------------------------------
#define BB   2
#define SS   2048
#define DD   2048
#define HQ   32
#define HKV  8
#define DH   64
#define MM   (BB * SS)          // 4096 tokens
#define NQKV 3072               // 2048 q + 512 k + 512 v

// 0.125 (1/sqrt(DH)) * log2(e) — folded into Wq at prep time so the
// QK^T MFMA output is directly the exp2 argument (softmax shift-invariance
// makes any constant bias a pure power-of-2 factor that cancels in o/l).
#define QSCALE 0.18033688011112042f

// ---------------------------------------------------------------------------
// Kernel: merged preprocessing — one launch instead of three.
// Block ranges:
//   [0, 8192)      : fp32->bf16 cast of x (1024 elems/block)
//   [8192, 12288)  : Wq transpose+cast (scaled by QSCALE), 2048x2048
//   [12288, 16384) : Wo transpose+cast, 2048x2048
//   [16384, 17408) : Wk transpose+cast, 2048x512
//   [17408, 18432) : Wv transpose+cast, 2048x512
// All independent; merging removes 2 launch/drain boundaries and lets the
// small transpose grids fill CUs alongside the cast.
// ---------------------------------------------------------------------------
__global__ __launch_bounds__(256) void prep(const float* __restrict__ x,
                                            const float* __restrict__ Wq,
                                            const float* __restrict__ Wk,
                                            const float* __restrict__ Wv,
                                            const float* __restrict__ Wo,
                                            unsigned short* __restrict__ xb,
                                            unsigned short* __restrict__ WqkvT,
                                            unsigned short* __restrict__ WoT) {
    const int bid = blockIdx.x;
    if (bid < 8192) {                       // ---- cast x -> xb (vectorized) ----
        const int i = (bid * 256 + threadIdx.x) * 4;   // exactly covers MM*DD
        const float4 f = *(const float4*)(x + i);
        us4 o;
        o[0] = f2bf(f.x); o[1] = f2bf(f.y); o[2] = f2bf(f.z); o[3] = f2bf(f.w);
        *(us4*)(xb + i) = o;
        return;
    }
    // ---- weight transpose + cast (+ optional scale) ----
    const float* src; unsigned short* dst; int C, bx, by; float scl = 1.0f;
    int r = bid - 8192;
    if (r < 4096) {
        src = Wq; dst = WqkvT; C = 2048; bx = r & 63; by = r >> 6; scl = QSCALE;
    } else if (r < 8192) {
        r -= 4096; src = Wo; dst = WoT; C = 2048; bx = r & 63; by = r >> 6;
    } else if (r < 9216) {
        r -= 8192; src = Wk; dst = WqkvT + (size_t)2048 * 2048; C = 512; bx = r & 15; by = r >> 4;
    } else {
        r -= 9216; src = Wv; dst = WqkvT + (size_t)2560 * 2048; C = 512; bx = r & 15; by = r >> 4;
    }
    const int R = 2048;                     // all weight matrices have 2048 rows
    __shared__ __attribute__((aligned(16))) float tile[32][33];
    const int c0 = bx * 32, r0 = by * 32;
    const int tx = threadIdx.x & 31, ty = threadIdx.x >> 5;
    #pragma unroll
    for (int dy = 0; dy < 32; dy += 8)
        tile[ty + dy][tx] = src[(size_t)(r0 + ty + dy) * C + c0 + tx];
    __syncthreads();
    #pragma unroll
    for (int dy = 0; dy < 32; dy += 8)
        dst[(size_t)(c0 + ty + dy) * R + r0 + tx] = f2bf(tile[tx][ty + dy] * scl);
}

// ---------------------------------------------------------------------------
// Kernel: transpose V slice of QKV into Vt[b][kvh][d][s]  (bf16 -> bf16)
// grid = (S/32, DH/32, B*HKV), block = 256 (32x8)
// ---------------------------------------------------------------------------
__global__ __launch_bounds__(256) void transpose_v(const unsigned short* __restrict__ qkv,
                                                   unsigned short* __restrict__ vt) {
    __shared__ __attribute__((aligned(16))) unsigned short tile[32][33];
    const int s0 = blockIdx.x * 32, d0 = blockIdx.y * 32;
    const int bh = blockIdx.z;
    const int b = bh >> 3, kvh = bh & 7;
    const int tx = threadIdx.x & 31, ty = threadIdx.x >> 5;
    #pragma unroll
    for (int dy = 0; dy < 32; dy += 8)
        tile[ty + dy][tx] =
            qkv[(size_t)(b * SS + s0 + ty + dy) * NQKV + 2560 + kvh * DH + d0 + tx];
    __syncthreads();
    #pragma unroll
    for (int dy = 0; dy < 32; dy += 8)
        vt[(size_t)((b * HKV + kvh) * DH + d0 + ty + dy) * SS + s0 + tx] =
            tile[tx][ty + dy];
}

// ---------------------------------------------------------------------------
// Kernel: bf16 GEMM, C[M][N] = A[M][K] * Bt[N][K]^T
// 128x128 tile, BK=64, 4 waves (2x2 of 64x64), 16x16x32 MFMA.
// LDS chunk-XOR swizzle -> conflict-free b128 frag reads w/ gld_lds16 staging.
// ---------------------------------------------------------------------------
template <int OUT_BF16>
__global__ __launch_bounds__(256) void gemm_bt(const unsigned short* __restrict__ A,
                                               const unsigned short* __restrict__ Bt,
                                               void* __restrict__ Cout,
                                               int M, int N, int K) {
    __shared__ __attribute__((aligned(16))) unsigned short As[128 * 64];
    __shared__ __attribute__((aligned(16))) unsigned short Bs[128 * 64];
    const int bm = blockIdx.x, bn = blockIdx.y;
    const int tid = threadIdx.x;
    const int wave = tid >> 6, lane = tid & 63;
    const int wm = (wave >> 1) * 64, wn = (wave & 1) * 64;
    const int g = lane >> 4, l15 = lane & 15;
    const int sr = lane >> 3;
    const int sc8 = ((lane & 7) ^ (sr & 7)) * 8;   // swizzled source chunk
    const int r7 = l15 & 7;

    f32x4 acc[4][4] = {};
    const unsigned short* aBase = A  + (size_t)(bm * 128) * K;
    const unsigned short* bBase = Bt + (size_t)(bn * 128) * K;

    for (int kt = 0; kt < K; kt += 64) {
        __syncthreads();
        #pragma unroll
        for (int j = 0; j < 4; ++j) {
            const int i = wave * 4 + j;                      // wave-uniform
            gld_lds16(aBase + (size_t)(i * 8 + sr) * K + kt + sc8, &As[i * 512]);
            gld_lds16(bBase + (size_t)(i * 8 + sr) * K + kt + sc8, &Bs[i * 512]);
        }
        __syncthreads();
        #pragma unroll
        for (int ks = 0; ks < 2; ++ks) {
            bf16x8 af[4], bfr[4];
            #pragma unroll
            for (int t = 0; t < 4; ++t) {
                af[t]  = *(const bf16x8*)&As[(wm + t * 16 + l15) * 64 + ((ks * 4 + g) ^ r7) * 8];
                bfr[t] = *(const bf16x8*)&Bs[(wn + t * 16 + l15) * 64 + ((ks * 4 + g) ^ r7) * 8];
            }
            #pragma unroll
            for (int i = 0; i < 4; ++i)
                #pragma unroll
                for (int j = 0; j < 4; ++j)
                    acc[i][j] = __builtin_amdgcn_mfma_f32_16x16x32_bf16(
                        af[i], bfr[j], acc[i][j], 0, 0, 0);
        }
    }
    // epilogue: C/D layout col = lane&15, row = (lane>>4)*4 + reg
    #pragma unroll
    for (int i = 0; i < 4; ++i) {
        #pragma unroll
        for (int j = 0; j < 4; ++j) {
            const int col = bn * 128 + wn + j * 16 + l15;
            #pragma unroll
            for (int r = 0; r < 4; ++r) {
                const int row = bm * 128 + wm + i * 16 + g * 4 + r;
                const float v = acc[i][j][r];
                if (OUT_BF16)
                    ((unsigned short*)Cout)[(size_t)row * N + col] = f2bf(v);
                else
                    ((float*)Cout)[(size_t)row * N + col] = v;
            }
        }
    }
}

// ---------------------------------------------------------------------------
// Kernel: flash attention v11 — v9 body + K-loop unrolled x2.
// v10 post-mortem: explicit interleave was neutral -> schedule-insensitive;
// MfmaUtil+VALUBusy ~95% (issue-serialized pipes). Remaining reducible VALU
// is addressing: unrolling x2 makes the double-buffer index compile-time, so
// all 16 LDS read addresses per tile become loop-invariant VGPRs + immediate
// ds offsets (removes ~16 v_add/tile). Epilogue uses v_rcp.
// grid = (S/128, HQ, B), block = 256 (4 waves x 32 q)
// ---------------------------------------------------------------------------
__global__ __launch_bounds__(256, 4) void flash_attn(const unsigned short* __restrict__ qkv,
                                                     const unsigned short* __restrict__ vt,
                                                     unsigned short* __restrict__ ctx) {
    __shared__ __attribute__((aligned(16))) unsigned short Ks[2][64 * 64];   // [permuted key][dh] swz
    __shared__ __attribute__((aligned(16))) unsigned short Vs[2][64 * 64];   // [dh][key] swz

    const int qt = blockIdx.x, h = blockIdx.y, b = blockIdx.z;
    const int kvh = h >> 2;   // NUM_REP = 4
    const int tid = threadIdx.x, wave = tid >> 6, lane = tid & 63;
    const int g = lane >> 4, l15 = lane & 15;
    const int sr = lane >> 3;
    const int sc8 = ((lane & 7) ^ (sr & 7)) * 8;
    const int r7 = l15 & 7;
    const int qb = qt * 128 + wave * 32;

    const unsigned short* kbase = qkv + (size_t)(b * SS) * NQKV + 2048 + kvh * DH;
    const unsigned short* vbase = vt + (size_t)((b * HKV + kvh) * DH) * SS;

    // Q fragments, B-operand layout (n-col = l15, k = g*8+j): [q n-tile][k-half]
    bf16x8 qf[2][2];
    #pragma unroll
    for (int n = 0; n < 2; ++n)
        #pragma unroll
        for (int kh = 0; kh < 2; ++kh)
            qf[n][kh] = *(const bf16x8*)(qkv +
                (size_t)(b * SS + qb + n * 16 + l15) * NQKV + h * DH + kh * 32 + g * 8);

    // all-ones B fragment for the denominator MFMA (any layout: every elem 1)
    bf16x8 ones;
    #pragma unroll
    for (int i = 0; i < 8; ++i) ones[i] = (__bf16)1.0f;

    // kernel-lifetime zero C-operand for QK chains (never written)
    const f32x4 z4 = {0.0f, 0.0f, 0.0f, 0.0f};

    // per-lane staging pointers (advanced by constant each iter; no per-iter mul)
    const unsigned short* sp[4];
    size_t sadv;
    if (wave < 2) {
        #pragma unroll
        for (int j = 0; j < 4; ++j) {
            const int rho = (wave * 4 + j) * 8 + sr;       // LDS row this lane fills
            // bit-swap: rho=[p,h,g1,g0,r1,r0] -> physical key=[p,g1,g0,h,r1,r0]
            const int key = (rho & 0x23) | ((rho & 0x0C) << 1) | ((rho & 0x10) >> 2);
            sp[j] = kbase + (size_t)key * NQKV + sc8;
        }
        sadv = (size_t)64 * NQKV;          // next 64 keys
    } else {
        #pragma unroll
        for (int j = 0; j < 4; ++j)
            sp[j] = vbase + (size_t)(((wave - 2) * 4 + j) * 8 + sr) * SS + sc8;
        sadv = 64;                          // next 64 keys (columns of Vt)
    }

    #define STAGE(buf)                                                        \
        do {                                                                  \
            if (wave < 2) {                                                   \
                _Pragma("unroll")                                             \
                for (int j = 0; j < 4; ++j)                                   \
                    gld_lds16(sp[j], &Ks[buf][(wave * 4 + j) * 512]);         \
            } else {                                                          \
                _Pragma("unroll")                                             \
                for (int j = 0; j < 4; ++j)                                   \
                    gld_lds16(sp[j], &Vs[buf][((wave - 2) * 4 + j) * 512]);   \
            }                                                                 \
            _Pragma("unroll")                                                 \
            for (int j = 0; j < 4; ++j) sp[j] += sadv;                        \
        } while (0)

    f32x4 oacc[2][4] = {};        // [q m-tile][dh n-tile]
    f32x4 lacc[2] = {};           // denominator accum: lacc[m][r] = rowsum(q=m*16+g*4+r)

    // one 64-key tile: QK(K=64) -> exp2 -> pack -> PV, per 32-key chunk p.
    #define TILE(BUF)                                                                          \
        do {                                                                                   \
            const unsigned short* ks = Ks[BUF];                                                \
            const unsigned short* vs = Vs[BUF];                                                \
            _Pragma("unroll")                                                                  \
            for (int p = 0; p < 2; ++p) {                                                      \
                uint4 pk4[2];                                                                  \
                _Pragma("unroll")                                                              \
                for (int hh = 0; hh < 2; ++hh) {                                               \
                    const int t = 2 * p + hh;                                                  \
                    bf16x8 kf0 = *(const bf16x8*)&ks[(t * 16 + l15) * 64 + ((g) ^ r7) * 8];    \
                    bf16x8 kf1 = *(const bf16x8*)&ks[(t * 16 + l15) * 64 + ((4 + g) ^ r7) * 8];\
                    _Pragma("unroll")                                                          \
                    for (int n = 0; n < 2; ++n) {                                              \
                        f32x4 c = __builtin_amdgcn_mfma_f32_16x16x32_bf16(                     \
                            kf0, qf[n][0], z4, 0, 0, 0);                                       \
                        c = __builtin_amdgcn_mfma_f32_16x16x32_bf16(                           \
                            kf1, qf[n][1], c, 0, 0, 0);                                        \
                        f32x4 pe;                                                              \
                        pe[0] = __builtin_amdgcn_exp2f(c[0]);                                  \
                        pe[1] = __builtin_amdgcn_exp2f(c[1]);                                  \
                        pe[2] = __builtin_amdgcn_exp2f(c[2]);                                  \
                        pe[3] = __builtin_amdgcn_exp2f(c[3]);                                  \
                        const unsigned int lo = pk_bf16_trunc(pe[0], pe[1]);                   \
                        const unsigned int hi = pk_bf16_trunc(pe[2], pe[3]);                   \
                        if (hh == 0) { pk4[n].x = lo; pk4[n].y = hi; }                         \
                        else         { pk4[n].z = lo; pk4[n].w = hi; }                         \
                    }                                                                          \
                }                                                                              \
                __builtin_amdgcn_s_setprio(1);                                                 \
                _Pragma("unroll")                                                              \
                for (int nt = 0; nt < 4; ++nt) {                                               \
                    bf16x8 vf = *(const bf16x8*)&vs[(nt * 16 + l15) * 64 +                     \
                                                    (((p << 2) + g) ^ r7) * 8];                \
                    _Pragma("unroll")                                                          \
                    for (int m = 0; m < 2; ++m) {                                              \
                        union { uint4 u; bf16x8 v; } pa; pa.u = pk4[m];                        \
                        oacc[m][nt] = __builtin_amdgcn_mfma_f32_16x16x32_bf16(                 \
                            pa.v, vf, oacc[m][nt], 0, 0, 0);                                   \
                        if (nt == 0)                                                           \
                            lacc[m] = __builtin_amdgcn_mfma_f32_16x16x32_bf16(                 \
                                pa.v, ones, lacc[m], 0, 0, 0);                                 \
                    }                                                                          \
                }                                                                              \
                __builtin_amdgcn_s_setprio(0);                                                 \
            }                                                                                  \
        } while (0)

    STAGE(0);

    // unrolled x2: buffer index compile-time -> LDS addrs loop-invariant.
    // 32 tiles total; stages: init(t0) + 16x(t odd) + 15x(t even) = 32.
    #pragma unroll 1
    for (int kt2 = 0; kt2 < 16; ++kt2) {
        __syncthreads();                 // vmcnt(0) drain -> buf0 ready
        STAGE(1);                        // prefetch tile 2*kt2+1
        TILE(0);
        __syncthreads();                 // buf1 ready; buf0 reads done
        if (kt2 < 15) STAGE(0);          // prefetch tile 2*kt2+2
        TILE(1);
    }

    // normalize + write: lane (g,l15) holds O[q = m*16+g*4+r][dh = nt*16+l15];
    // lacc[m][r] is the matching row denominator in the SAME lane (ones-MFMA
    // C/D layout row = g*4+r) -> no cross-lane reduce needed.
    #pragma unroll
    for (int m = 0; m < 2; ++m) {
        #pragma unroll
        for (int r = 0; r < 4; ++r) {
            const float inv = __builtin_amdgcn_rcpf(lacc[m][r]);
            const int token = b * SS + qb + m * 16 + g * 4 + r;
            #pragma unroll
            for (int nt = 0; nt < 4; ++nt)
                ctx[(size_t)token * (HQ * DH) + h * DH + nt * 16 + l15] =
                    f2bf(oacc[m][nt][r] * inv);
        }
    }
    #undef TILE
    #undef STAGE
}

// ---------------------------------------------------------------------------
// Launcher
// ---------------------------------------------------------------------------
extern "C" void kernel_launch(void* const* d_in, const int* in_sizes, int n_in,
                              void* d_out, int out_size, void* d_ws, size_t ws_size,
                              hipStream_t stream) {
    (void)in_sizes; (void)n_in; (void)out_size; (void)ws_size;
    const float* x  = (const float*)d_in[0];
    const float* Wq = (const float*)d_in[1];
    const float* Wk = (const float*)d_in[2];
    const float* Wv = (const float*)d_in[3];
    const float* Wo = (const float*)d_in[4];
    float* out = (float*)d_out;

    char* ws = (char*)d_ws;
    unsigned short* xb     = (unsigned short*)(ws);                         // 16 MB
    unsigned short* WqkvT  = (unsigned short*)(ws + 16777216);              // 12 MB  [3072][2048]
    unsigned short* WoT    = (unsigned short*)(ws + 29360128);              // 8 MB   [2048][2048]
    unsigned short* QKV    = (unsigned short*)(ws + 37748736);              // 24 MB  [4096][3072]
    unsigned short* Vt     = (unsigned short*)(ws + 62914560);              // 4 MB   [16][64][2048]
    unsigned short* ctx    = (unsigned short*)(ws + 67108864);              // 16 MB  [4096][2048]
    // total 80 MB

    // 1) merged preprocessing: x cast + all four weight transposes (one launch)
    prep<<<18432, 256, 0, stream>>>(x, Wq, Wk, Wv, Wo, xb, WqkvT, WoT);

    // 2) fused QKV projection: [4096,2048] @ [2048,3072] -> QKV bf16
    gemm_bt<1><<<dim3(32, 24), 256, 0, stream>>>(xb, WqkvT, QKV, MM, NQKV, DD);

    // 3) V transpose for PV fragment layout
    transpose_v<<<dim3(64, 2, 16), 256, 0, stream>>>(QKV, Vt);

    // 4) flash attention v11 -> ctx bf16
    flash_attn<<<dim3(16, 32, 2), 256, 0, stream>>>(QKV, Vt, ctx);

    // 5) output projection: [4096,2048] @ [2048,2048] -> out fp32
    gemm_bt<0><<<dim3(32, 16), 256, 0, stream>>>(ctx, WoT, out, MM, DD, DD);
}